// Round 1
// baseline (291.732 us; speedup 1.0000x reference)
//
#include <hip/hip_runtime.h>

// Causal MHA forward: B=2 H=16 T=2048 DH=64, fp32 in/out, bf16 MFMA math.
// Flash-attention: 4 waves/block, wave owns 16 q rows, KBLK=32,
// mfma_f32_16x16x32_bf16 for QK^T and PV. Online softmax per C/D row.

constexpr int Bc = 2, Hc = 16, Tc = 2048, Dc = 64;
constexpr float SCALE = 0.125f; // 64^-0.5

typedef __attribute__((__ext_vector_type__(8))) __bf16 bf16x8;
typedef __attribute__((__ext_vector_type__(4))) float f32x4;

__global__ __launch_bounds__(256, 2) void attn_fwd_kernel(
    const float* __restrict__ Q,
    const float* __restrict__ K,
    const float* __restrict__ V,
    float* __restrict__ O)
{
  const int tid  = threadIdx.x;
  const int wave = tid >> 6;
  const int lane = tid & 63;
  const int l16  = lane & 15;   // MFMA "col" / frag row
  const int g    = lane >> 4;   // 0..3

  const int bid   = blockIdx.x;
  const int qtile = bid & 31;   // T/64 = 32 q-tiles per head
  const int head  = bid >> 5;   // b*H + h, 0..31
  const int b     = head >> 4;
  const int h     = head & 15;

  const int q0 = qtile * 64 + wave * 16;  // first q row owned by this wave

  const size_t hoff = (size_t)head * Tc * Dc;
  const float* Qb = Q + hoff;
  const float* Kb = K + hoff;
  const float* Vb = V + hoff;

  // Q fragments (A operand): lane holds Q[q0 + l16][c*32 + g*8 + j], scaled.
  bf16x8 qf[2];
  {
    const float* qrow = Qb + (size_t)(q0 + l16) * Dc + g * 8;
    #pragma unroll
    for (int c = 0; c < 2; ++c)
      #pragma unroll
      for (int j = 0; j < 8; ++j)
        qf[c][j] = (__bf16)(qrow[c * 32 + j] * SCALE);
  }

  // O accumulator: 4 d-tiles of 16; C/D layout row q = g*4+r, col d = dt*16+l16.
  f32x4 o_acc[4] = {};
  float m_run[4], l_run[4];
  #pragma unroll
  for (int r = 0; r < 4; ++r) { m_run[r] = -1e30f; l_run[r] = 0.f; }

  // Per-wave P transpose buffer (C/D layout -> A-frag layout). 4 KB total.
  __shared__ __bf16 p_lds[4][16][32];

  const int n_iter = q0 / 32 + 1;  // last k needed = q0+15 < (q0/32+1)*32
  for (int it = 0; it < n_iter; ++it) {
    const int kv0 = it * 32;

    // K fragments (B operand of S = Q·K^T): same per-lane indexing as Q.
    bf16x8 kf0[2], kf1[2];
    {
      const float* k0 = Kb + (size_t)(kv0 + l16) * Dc + g * 8;
      const float* k1 = k0 + 16 * Dc;
      #pragma unroll
      for (int c = 0; c < 2; ++c)
        #pragma unroll
        for (int j = 0; j < 8; ++j) {
          kf0[c][j] = (__bf16)k0[c * 32 + j];
          kf1[c][j] = (__bf16)k1[c * 32 + j];
        }
    }

    f32x4 s0 = {0.f, 0.f, 0.f, 0.f};
    f32x4 s1 = {0.f, 0.f, 0.f, 0.f};
    s0 = __builtin_amdgcn_mfma_f32_16x16x32_bf16(qf[0], kf0[0], s0, 0, 0, 0);
    s0 = __builtin_amdgcn_mfma_f32_16x16x32_bf16(qf[1], kf0[1], s0, 0, 0, 0);
    s1 = __builtin_amdgcn_mfma_f32_16x16x32_bf16(qf[0], kf1[0], s1, 0, 0, 0);
    s1 = __builtin_amdgcn_mfma_f32_16x16x32_bf16(qf[1], kf1[1], s1, 0, 0, 0);

    // Causal mask — only the final tile is ever partial.
    if (kv0 + 31 > q0) {
      #pragma unroll
      for (int r = 0; r < 4; ++r) {
        const int qa = q0 + g * 4 + r;
        if (kv0 + l16 > qa)      s0[r] = -INFINITY;
        if (kv0 + 16 + l16 > qa) s1[r] = -INFINITY;
      }
    }

    // Online softmax: row stats across the 16 lanes sharing g.
    float p0[4], p1[4];
    #pragma unroll
    for (int r = 0; r < 4; ++r) {
      float mx = fmaxf(s0[r], s1[r]);
      #pragma unroll
      for (int off = 8; off >= 1; off >>= 1)
        mx = fmaxf(mx, __shfl_xor(mx, off, 64));
      const float mn = fmaxf(m_run[r], mx);
      const float f  = __expf(m_run[r] - mn);
      m_run[r] = mn;
      p0[r] = __expf(s0[r] - mn);
      p1[r] = __expf(s1[r] - mn);
      float sum = p0[r] + p1[r];
      #pragma unroll
      for (int off = 8; off >= 1; off >>= 1)
        sum += __shfl_xor(sum, off, 64);
      l_run[r] = l_run[r] * f + sum;
      #pragma unroll
      for (int dt = 0; dt < 4; ++dt) o_acc[dt][r] *= f;
    }

    // P (C/D layout) -> LDS -> A-frag layout for PV.
    #pragma unroll
    for (int r = 0; r < 4; ++r) {
      p_lds[wave][g * 4 + r][l16]      = (__bf16)p0[r];
      p_lds[wave][g * 4 + r][16 + l16] = (__bf16)p1[r];
    }
    bf16x8 pf = *(const bf16x8*)&p_lds[wave][l16][g * 8];

    // PV: B operand vf[j] = V[kv0 + g*8 + j][dt*16 + l16].
    #pragma unroll
    for (int dt = 0; dt < 4; ++dt) {
      bf16x8 vf;
      const float* vp = Vb + (size_t)(kv0 + g * 8) * Dc + dt * 16 + l16;
      #pragma unroll
      for (int j = 0; j < 8; ++j) vf[j] = (__bf16)vp[j * Dc];
      o_acc[dt] = __builtin_amdgcn_mfma_f32_16x16x32_bf16(pf, vf, o_acc[dt], 0, 0, 0);
    }
  }

  // Epilogue: out[b][q][h*64 + d] = o/l.
  #pragma unroll
  for (int r = 0; r < 4; ++r) {
    const float inv = 1.f / l_run[r];
    float* orow = O + ((size_t)b * Tc + (q0 + g * 4 + r)) * (Hc * Dc) + h * Dc;
    #pragma unroll
    for (int dt = 0; dt < 4; ++dt)
      orow[dt * 16 + l16] = o_acc[dt][r] * inv;
  }
}

extern "C" void kernel_launch(void* const* d_in, const int* in_sizes, int n_in,
                              void* d_out, int out_size, void* d_ws, size_t ws_size,
                              hipStream_t stream) {
  const float* q = (const float*)d_in[0];
  const float* k = (const float*)d_in[1];
  const float* v = (const float*)d_in[2];
  // d_in[3] attention_mask: all-true; d_in[4] causal_mask: tril — both
  // implemented analytically in-kernel.
  float* out = (float*)d_out;

  dim3 grid(Bc * Hc * (Tc / 64));  // 1024 blocks
  dim3 block(256);                 // 4 waves
  hipLaunchKernelGGL(attn_fwd_kernel, grid, block, 0, stream, q, k, v, out);
}

// Round 2
// 138.157 us; speedup vs baseline: 2.1116x; 2.1116x over previous
//
#include <hip/hip_runtime.h>

// Causal MHA forward: B=2 H=16 T=2048 DH=64, fp32 in/out, bf16 MFMA math.
// Flash-attention: 4 waves/block, wave owns 16 q rows, KBLK=64.
// K and V staged cooperatively in LDS (bf16, XOR-swizzled; V transposed).

constexpr int Bc = 2, Hc = 16, Tc = 2048, Dc = 64;
constexpr float SCALE = 0.125f; // 64^-0.5

typedef __attribute__((__ext_vector_type__(8))) __bf16 bf16x8;
typedef __attribute__((__ext_vector_type__(4))) float f32x4;

__global__ __launch_bounds__(256, 2) void attn_fwd_kernel(
    const float* __restrict__ Q,
    const float* __restrict__ K,
    const float* __restrict__ V,
    float* __restrict__ O)
{
  const int tid  = threadIdx.x;
  const int wave = tid >> 6;
  const int lane = tid & 63;
  const int l16  = lane & 15;   // MFMA frag row / C-D col
  const int g    = lane >> 4;   // 0..3

  const int bid   = blockIdx.x;
  const int qtile = bid & 31;   // 32 q-tiles of 64 per head
  const int head  = bid >> 5;   // b*H + h
  const int b     = head >> 4;
  const int h     = head & 15;

  const int q0 = qtile * 64 + wave * 16;  // first q row of this wave

  const size_t hoff = (size_t)head * Tc * Dc;
  const float* Qb = Q + hoff;
  const float* Kb = K + hoff;
  const float* Vb = V + hoff;

  // K tile [64 k][64 d] bf16, rows 128 B, byte-col ^ ((row&7)<<4) swizzle.
  __shared__ __bf16 Kl[64 * 64];
  // V tile transposed [64 d][64 k] bf16, same swizzle.
  __shared__ __bf16 Vt[64 * 64];
  // Per-wave P buffer [16 q][64 k] bf16, same swizzle.
  __shared__ __bf16 Pl[4][16 * 64];

  // Q fragments (A operand): lane holds Q[q0+l16][c*32 + g*8 + j] * SCALE.
  bf16x8 qf[2];
  {
    const float* qrow = Qb + (size_t)(q0 + l16) * Dc + g * 8;
    #pragma unroll
    for (int c = 0; c < 2; ++c)
      #pragma unroll
      for (int j = 0; j < 8; ++j)
        qf[c][j] = (__bf16)(qrow[c * 32 + j] * SCALE);
  }

  f32x4 o_acc[4] = {};
  float m_run[4], l_run[4];
  #pragma unroll
  for (int r = 0; r < 4; ++r) { m_run[r] = -1e30f; l_run[r] = 0.f; }

  const int krow = tid >> 2;   // staging: row this thread loads
  const int seg  = tid & 3;    // 16-float segment within the row
  const int kswz = (krow & 7) << 4;

  const int n_iter = qtile + 1;
  for (int it = 0; it < n_iter; ++it) {
    const int kv0 = it * 64;

    __syncthreads();  // previous tile's LDS reads done

    // ---- Stage K tile (row-major bf16, swizzled) ----
    {
      const float4* kp4 = (const float4*)(Kb + (size_t)(kv0 + krow) * Dc + seg * 16);
      #pragma unroll
      for (int c = 0; c < 2; ++c) {
        float4 a = kp4[2 * c], bb = kp4[2 * c + 1];
        bf16x8 t;
        t[0] = (__bf16)a.x;  t[1] = (__bf16)a.y;  t[2] = (__bf16)a.z;  t[3] = (__bf16)a.w;
        t[4] = (__bf16)bb.x; t[5] = (__bf16)bb.y; t[6] = (__bf16)bb.z; t[7] = (__bf16)bb.w;
        *(bf16x8*)((char*)Kl + krow * 128 + ((seg * 32 + c * 16) ^ kswz)) = t;
      }
    }
    // ---- Stage V tile transposed (Vt[d][k], swizzled) ----
    {
      const float4* vp4 = (const float4*)(Vb + (size_t)(kv0 + krow) * Dc + seg * 16);
      #pragma unroll
      for (int c = 0; c < 4; ++c) {
        float4 a = vp4[c];
        float vals[4] = {a.x, a.y, a.z, a.w};
        #pragma unroll
        for (int i2 = 0; i2 < 4; ++i2) {
          const int i = c * 4 + i2;          // 0..15, d = seg*16 + i
          const int d = seg * 16 + i;
          *(__bf16*)((char*)Vt + d * 128 + ((2 * krow) ^ ((i & 7) << 4))) = (__bf16)vals[i2];
        }
      }
    }
    __syncthreads();  // tile staged

    // ---- QK^T: 4 k-subtiles of 16 ----
    const bool partial = (kv0 + 63 > q0);  // only the final iteration
    f32x4 sacc[4];
    #pragma unroll
    for (int s = 0; s < 4; ++s) sacc[s] = f32x4{0.f, 0.f, 0.f, 0.f};
    #pragma unroll
    for (int s = 0; s < 4; ++s) {
      if (partial && s > wave) {           // wave-uniform: fully masked subtile
        sacc[s] = f32x4{-INFINITY, -INFINITY, -INFINITY, -INFINITY};
        continue;
      }
      const int row = s * 16 + l16;
      const int swz = (row & 7) << 4;
      bf16x8 k0 = *(const bf16x8*)((char*)Kl + row * 128 + ((g * 16) ^ swz));
      bf16x8 k1 = *(const bf16x8*)((char*)Kl + row * 128 + ((64 + g * 16) ^ swz));
      sacc[s] = __builtin_amdgcn_mfma_f32_16x16x32_bf16(qf[0], k0, sacc[s], 0, 0, 0);
      sacc[s] = __builtin_amdgcn_mfma_f32_16x16x32_bf16(qf[1], k1, sacc[s], 0, 0, 0);
    }
    if (partial) {
      // Only the s == wave subtile straddles the diagonal.
      const int s = wave;
      #pragma unroll
      for (int r = 0; r < 4; ++r)
        if (kv0 + s * 16 + l16 > q0 + g * 4 + r) sacc[s][r] = -INFINITY;
    }

    // ---- Online softmax per row (16 lanes sharing g hold the row) ----
    #pragma unroll
    for (int r = 0; r < 4; ++r) {
      float mx = fmaxf(fmaxf(sacc[0][r], sacc[1][r]), fmaxf(sacc[2][r], sacc[3][r]));
      #pragma unroll
      for (int off = 8; off >= 1; off >>= 1)
        mx = fmaxf(mx, __shfl_xor(mx, off, 64));
      const float mn = fmaxf(m_run[r], mx);
      const float f  = __expf(m_run[r] - mn);
      m_run[r] = mn;
      float p[4];
      float sum = 0.f;
      #pragma unroll
      for (int s = 0; s < 4; ++s) { p[s] = __expf(sacc[s][r] - mn); sum += p[s]; }
      #pragma unroll
      for (int off = 8; off >= 1; off >>= 1)
        sum += __shfl_xor(sum, off, 64);
      l_run[r] = l_run[r] * f + sum;
      #pragma unroll
      for (int dt = 0; dt < 4; ++dt) o_acc[dt][r] *= f;
      // P -> per-wave LDS (swizzled), C/D layout -> A-frag layout.
      const int prow = g * 4 + r;
      char* pb = (char*)Pl[wave] + prow * 128;
      const int pswz = (prow & 7) << 4;
      #pragma unroll
      for (int s = 0; s < 4; ++s)
        *(__bf16*)(pb + ((2 * (s * 16 + l16)) ^ pswz)) = (__bf16)p[s];
    }

    // ---- PV: O += P(16x64) * V(64x64) ----
    const int lswz = (l16 & 7) << 4;
    bf16x8 pf0 = *(const bf16x8*)((char*)Pl[wave] + l16 * 128 + ((g * 16) ^ lswz));
    bf16x8 pf1 = *(const bf16x8*)((char*)Pl[wave] + l16 * 128 + ((64 + g * 16) ^ lswz));
    #pragma unroll
    for (int dt = 0; dt < 4; ++dt) {
      const int vrow = dt * 16 + l16;
      const int vswz = (vrow & 7) << 4;
      bf16x8 v0 = *(const bf16x8*)((char*)Vt + vrow * 128 + ((g * 16) ^ vswz));
      bf16x8 v1 = *(const bf16x8*)((char*)Vt + vrow * 128 + ((64 + g * 16) ^ vswz));
      o_acc[dt] = __builtin_amdgcn_mfma_f32_16x16x32_bf16(pf0, v0, o_acc[dt], 0, 0, 0);
      o_acc[dt] = __builtin_amdgcn_mfma_f32_16x16x32_bf16(pf1, v1, o_acc[dt], 0, 0, 0);
    }
  }

  // ---- Epilogue: out[b][q][h*64 + d] = o / l ----
  #pragma unroll
  for (int r = 0; r < 4; ++r) {
    const float inv = 1.f / l_run[r];
    float* orow = O + ((size_t)b * Tc + (q0 + g * 4 + r)) * (Hc * Dc) + h * Dc;
    #pragma unroll
    for (int dt = 0; dt < 4; ++dt)
      orow[dt * 16 + l16] = o_acc[dt][r] * inv;
  }
}

extern "C" void kernel_launch(void* const* d_in, const int* in_sizes, int n_in,
                              void* d_out, int out_size, void* d_ws, size_t ws_size,
                              hipStream_t stream) {
  const float* q = (const float*)d_in[0];
  const float* k = (const float*)d_in[1];
  const float* v = (const float*)d_in[2];
  float* out = (float*)d_out;

  dim3 grid(Bc * Hc * (Tc / 64));  // 1024 blocks
  dim3 block(256);                 // 4 waves
  hipLaunchKernelGGL(attn_fwd_kernel, grid, block, 0, stream, q, k, v, out);
}

// Round 3
// 109.130 us; speedup vs baseline: 2.6732x; 1.2660x over previous
//
#include <hip/hip_runtime.h>

// Causal MHA forward: B=2 H=16 T=2048 DH=64, fp32 in/out, bf16 MFMA math.
// Flash-attention, 4 waves/block, wave owns 16 q rows, KBLK=64.
// Swapped QK^T (mfma(K,Q)) => per-lane q-row slices, softmax + P fully
// in registers; PV B-operand read pi-matched from swizzled Vt LDS.

constexpr int Bc = 2, Hc = 16, Tc = 2048, Dc = 64;
constexpr float QSCALE = 0.125f * 1.44269504088896340736f; // DH^-0.5 * log2(e)

typedef __attribute__((__ext_vector_type__(8))) __bf16 bf16x8;
typedef __attribute__((__ext_vector_type__(4))) __bf16 bf16x4;
typedef __attribute__((__ext_vector_type__(4))) float f32x4;

__global__ __launch_bounds__(256, 4) void attn_fwd_kernel(
    const float* __restrict__ Q,
    const float* __restrict__ K,
    const float* __restrict__ V,
    float* __restrict__ O)
{
  const int tid  = threadIdx.x;
  const int wave = tid >> 6;
  const int lane = tid & 63;
  const int l16  = lane & 15;
  const int g    = lane >> 4;

  const int bid = blockIdx.x;
  const int rq  = bid & 31;
  // heavy/light pairing for load balance: 0,31,1,30,...
  const int qtile = (rq & 1) ? (31 - (rq >> 1)) : (rq >> 1);
  const int head  = bid >> 5;
  const int b = head >> 4, h = head & 15;

  const int q0 = qtile * 64 + wave * 16;

  const size_t hoff = (size_t)head * Tc * Dc;
  const float* Qb = Q + hoff;
  const float* Kb = K + hoff;
  const float* Vb = V + hoff;

  // K tile [64 k][64 d] bf16, 128 B rows, byte ^ ((k&7)<<4) swizzle.
  __shared__ __bf16 Kl[64 * 64];
  // V tile transposed [64 d][64 k] bf16, byte ^ ((d&7)<<4) swizzle.
  __shared__ __bf16 Vt[64 * 64];

  // Q as the B-operand frag of S^T = K·Q^T: lane l16 = q, regs = d = c*32+g*8+j.
  bf16x8 qf[2];
  {
    const float* qrow = Qb + (size_t)(q0 + l16) * Dc + g * 8;
    #pragma unroll
    for (int c = 0; c < 2; ++c)
      #pragma unroll
      for (int j = 0; j < 8; ++j)
        qf[c][j] = (__bf16)(qrow[c * 32 + j] * QSCALE);
  }

  // O accumulator: lane holds O[q = g*4+r][d = dt*16+l16].
  f32x4 o_acc[4] = {};
  // Softmax state for q-row l16 (replicated across the 4 g copies).
  float m_run = -1e30f, l_run = 0.f;

  const int krow = tid >> 2;  // staging row
  const int seg  = tid & 3;   // 16-float segment
  const int kswz = (krow & 7) << 4;

  const int n_iter = qtile + 1;
  for (int it = 0; it < n_iter; ++it) {
    const int kv0 = it * 64;

    __syncthreads();

    // ---- Stage K tile (row-major bf16, swizzled) ----
    {
      const float4* kp4 = (const float4*)(Kb + (size_t)(kv0 + krow) * Dc + seg * 16);
      #pragma unroll
      for (int c = 0; c < 2; ++c) {
        float4 a = kp4[2 * c], bb = kp4[2 * c + 1];
        bf16x8 t;
        t[0] = (__bf16)a.x;  t[1] = (__bf16)a.y;  t[2] = (__bf16)a.z;  t[3] = (__bf16)a.w;
        t[4] = (__bf16)bb.x; t[5] = (__bf16)bb.y; t[6] = (__bf16)bb.z; t[7] = (__bf16)bb.w;
        *(bf16x8*)((char*)Kl + krow * 128 + ((seg * 32 + c * 16) ^ kswz)) = t;
      }
    }
    // ---- Stage V transposed (Vt[d][k], swizzled) ----
    {
      const float4* vp4 = (const float4*)(Vb + (size_t)(kv0 + krow) * Dc + seg * 16);
      #pragma unroll
      for (int c = 0; c < 4; ++c) {
        float4 a = vp4[c];
        float vals[4] = {a.x, a.y, a.z, a.w};
        #pragma unroll
        for (int i2 = 0; i2 < 4; ++i2) {
          const int i = c * 4 + i2;          // d = seg*16 + i
          const int d = seg * 16 + i;
          *(__bf16*)((char*)Vt + d * 128 + ((2 * krow) ^ ((i & 7) << 4))) = (__bf16)vals[i2];
        }
      }
    }
    __syncthreads();

    const bool partial = (it == qtile);
    const int  ns = partial ? (wave + 1) : 4;  // live 16-k subtiles

    // ---- S^T = K·Q^T: sacc[s] row = k-in-subtile (g*4+r), col = q (l16) ----
    f32x4 sacc[4];
    #pragma unroll
    for (int s = 0; s < 4; ++s) {
      if (s < ns) {                       // wave-uniform branch
        f32x4 z = {0.f, 0.f, 0.f, 0.f};
        const int row = s * 16 + l16;
        const char* kb = (const char*)Kl + row * 128;
        const int swz = (row & 7) << 4;
        bf16x8 k0 = *(const bf16x8*)(kb + ((g * 16) ^ swz));
        bf16x8 k1 = *(const bf16x8*)(kb + ((64 + g * 16) ^ swz));
        z = __builtin_amdgcn_mfma_f32_16x16x32_bf16(k0, qf[0], z, 0, 0, 0);
        z = __builtin_amdgcn_mfma_f32_16x16x32_bf16(k1, qf[1], z, 0, 0, 0);
        sacc[s] = z;
      } else {
        sacc[s] = f32x4{-INFINITY, -INFINITY, -INFINITY, -INFINITY};
      }
    }
    // Causal mask (diag tile only): k_in_tile = s*16+g*4+r, q_in_tile = wave*16+l16.
    if (partial) {
      #pragma unroll
      for (int s = 0; s < 4; ++s)
        #pragma unroll
        for (int r = 0; r < 4; ++r)
          if (s * 16 + g * 4 + r > wave * 16 + l16) sacc[s][r] = -INFINITY;
    }

    // ---- Online softmax for q-row l16 (4 lanes share it via g) ----
    float mx = -INFINITY;
    #pragma unroll
    for (int s = 0; s < 4; ++s)
      #pragma unroll
      for (int r = 0; r < 4; ++r) mx = fmaxf(mx, sacc[s][r]);
    mx = fmaxf(mx, __shfl_xor(mx, 16, 64));
    mx = fmaxf(mx, __shfl_xor(mx, 32, 64));
    const float mn = fmaxf(m_run, mx);
    const float f  = __builtin_amdgcn_exp2f(m_run - mn);
    m_run = mn;

    float sum = 0.f;
    bf16x8 pa[2];
    #pragma unroll
    for (int c = 0; c < 2; ++c)
      #pragma unroll
      for (int j = 0; j < 8; ++j) {
        const float pv = __builtin_amdgcn_exp2f(sacc[2 * c + (j >> 2)][j & 3] - mn);
        sum += pv;
        pa[c][j] = (__bf16)pv;
      }
    sum += __shfl_xor(sum, 16, 64);
    sum += __shfl_xor(sum, 32, 64);
    l_run = l_run * f + sum;

    // Rescale O: factor for q = g*4+r lives at lane g*4+r.
    #pragma unroll
    for (int r = 0; r < 4; ++r) {
      const float fo = __shfl(f, g * 4 + r, 64);
      #pragma unroll
      for (int dt = 0; dt < 4; ++dt) o_acc[dt][r] *= fo;
    }

    // ---- PV: O += P(16x64) · V(64x64), both operands in pi k-order ----
    #pragma unroll
    for (int dt = 0; dt < 4; ++dt) {
      const int d = dt * 16 + l16;
      const char* vb = (const char*)Vt + d * 128;
      const int dsz = (d & 7) << 4;
      #pragma unroll
      for (int c = 0; c < 2; ++c) {
        union { bf16x8 v8; bf16x4 v4[2]; } u;
        u.v4[0] = *(const bf16x4*)(vb + ((2 * (32 * c + 4 * g)) ^ dsz));
        u.v4[1] = *(const bf16x4*)(vb + ((2 * (32 * c + 16 + 4 * g)) ^ dsz));
        o_acc[dt] = __builtin_amdgcn_mfma_f32_16x16x32_bf16(pa[c], u.v8, o_acc[dt], 0, 0, 0);
      }
    }
  }

  // ---- Epilogue: out[b][q][h*64+d] = o / l ----
  #pragma unroll
  for (int r = 0; r < 4; ++r) {
    const float il = __shfl(l_run, g * 4 + r, 64);
    const float inv = 1.f / il;
    float* orow = O + ((size_t)b * Tc + (q0 + g * 4 + r)) * (Hc * Dc) + h * Dc;
    #pragma unroll
    for (int dt = 0; dt < 4; ++dt)
      orow[dt * 16 + l16] = o_acc[dt][r] * inv;
  }
}

extern "C" void kernel_launch(void* const* d_in, const int* in_sizes, int n_in,
                              void* d_out, int out_size, void* d_ws, size_t ws_size,
                              hipStream_t stream) {
  const float* q = (const float*)d_in[0];
  const float* k = (const float*)d_in[1];
  const float* v = (const float*)d_in[2];
  float* out = (float*)d_out;

  dim3 grid(Bc * Hc * (Tc / 64));  // 1024 blocks
  dim3 block(256);                 // 4 waves
  hipLaunchKernelGGL(attn_fwd_kernel, grid, block, 0, stream, q, k, v, out);
}

// Round 4
// 53.266 us; speedup vs baseline: 5.4769x; 2.0488x over previous
//
#include <hip/hip_runtime.h>

// Causal MHA forward: B=2 H=16 T=2048 DH=64, fp32 in/out, bf16 MFMA math.
// Flash-attention, 4 waves/block, wave owns 16 q rows, KBLK=64.
// Swapped QK^T (mfma(K,Q)); P in registers; V^T stored as k-quads so PV
// B-operand reads are b64 at the bank floor. Per-CU balanced qtile map.
// T14: next tile's global loads issued before compute.

constexpr int Bc = 2, Hc = 16, Tc = 2048, Dc = 64;
constexpr float QSCALE = 0.125f * 1.44269504088896340736f; // DH^-0.5 * log2 e

typedef __attribute__((__ext_vector_type__(8))) __bf16 bf16x8;
typedef __attribute__((__ext_vector_type__(4))) __bf16 bf16x4;
typedef __attribute__((__ext_vector_type__(4))) float f32x4;

__global__ __launch_bounds__(256, 4) void attn_fwd_kernel(
    const float* __restrict__ Q,
    const float* __restrict__ K,
    const float* __restrict__ V,
    float* __restrict__ O)
{
  const int tid  = threadIdx.x;
  const int wave = tid >> 6;
  const int lane = tid & 63;
  const int l16  = lane & 15;
  const int g    = lane >> 4;

  // Balanced bid -> (head, qtile): blocks equal mod 256 share `head` and
  // get qtile set {b, 15-b, 16+b, 31-b} -> constant 66 tile-units per CU.
  const int bid  = blockIdx.x;
  const int head = bid & 31;
  const int vv   = bid >> 5;
  const int aq   = vv >> 3;
  const int bq   = vv & 7;
  int qtile;
  switch (aq) {
    case 0:  qtile = bq;      break;
    case 1:  qtile = 15 - bq; break;
    case 2:  qtile = 16 + bq; break;
    default: qtile = 31 - bq; break;
  }

  const int b = head >> 4, h = head & 15;
  const int q0 = qtile * 64 + wave * 16;

  const size_t hoff = (size_t)head * Tc * Dc;
  const float* Qb = Q + hoff;
  const float* Kb = K + hoff;
  const float* Vb = V + hoff;

  // K tile [64 k][64 d] bf16, 128 B rows, byte ^ ((k&7)<<4) swizzle.
  __shared__ __bf16 Kl[64 * 64];
  // V^T as k-quads: byte addr = kc*512 + ((d*8) ^ (kc<<3)) + (k&3)*2,
  // kc = k>>2. Reads (16 lanes span 128 B) and writes both at bank floor.
  __shared__ __bf16 Vt[64 * 64];

  // Q as B-operand frag of S^T = K·Q^T: lane l16 = q, regs d = c*32+g*8+j.
  bf16x8 qf[2];
  {
    const float* qrow = Qb + (size_t)(q0 + l16) * Dc + g * 8;
    #pragma unroll
    for (int c = 0; c < 2; ++c)
      #pragma unroll
      for (int j = 0; j < 8; ++j)
        qf[c][j] = (__bf16)(qrow[c * 32 + j] * QSCALE);
  }

  // O accumulator: lane holds O[q = g*4+r][d = dt*16+l16].
  f32x4 o_acc[4] = {};
  float m_run = -1e30f, l_run = 0.f;

  // Staging assignments.
  const int krow = tid >> 2;          // K: row, 16-float segment seg
  const int seg  = tid & 3;
  const int kswz = (krow & 7) << 4;
  const int vkb  = tid >> 4;          // V: k-quad (kc), d-quad
  const int vdb  = tid & 15;

  const int n_iter = qtile + 1;

  float4 kreg[4], vreg[4];
  // Prologue: load tile 0 into registers.
  {
    const float4* kp4 = (const float4*)(Kb + (size_t)krow * Dc + seg * 16);
    #pragma unroll
    for (int c = 0; c < 4; ++c) kreg[c] = kp4[c];
    const float* vb0 = Vb + (size_t)(vkb * 4) * Dc + vdb * 4;
    #pragma unroll
    for (int r = 0; r < 4; ++r) vreg[r] = *(const float4*)(vb0 + r * Dc);
  }

  for (int it = 0; it < n_iter; ++it) {
    __syncthreads();  // previous tile's LDS reads done

    // ---- Write staged registers to LDS ----
    #pragma unroll
    for (int hh = 0; hh < 2; ++hh) {
      const float* x0 = (const float*)&kreg[2 * hh];
      const float* x1 = (const float*)&kreg[2 * hh + 1];
      bf16x8 t;
      #pragma unroll
      for (int j = 0; j < 4; ++j) { t[j] = (__bf16)x0[j]; t[4 + j] = (__bf16)x1[j]; }
      *(bf16x8*)((char*)Kl + krow * 128 + ((seg * 32 + hh * 16) ^ kswz)) = t;
    }
    #pragma unroll
    for (int i = 0; i < 4; ++i) {
      bf16x4 t;
      #pragma unroll
      for (int r = 0; r < 4; ++r) t[r] = (__bf16)((const float*)&vreg[r])[i];
      const int d = vdb * 4 + i;
      *(bf16x4*)((char*)Vt + vkb * 512 + ((d * 8) ^ (vkb << 3))) = t;
    }
    __syncthreads();  // tile staged

    // ---- T14: issue next tile's global loads before compute ----
    if (it + 1 < n_iter) {
      const int kv1 = (it + 1) * 64;
      const float4* kp4 = (const float4*)(Kb + (size_t)(kv1 + krow) * Dc + seg * 16);
      #pragma unroll
      for (int c = 0; c < 4; ++c) kreg[c] = kp4[c];
      const float* vb0 = Vb + (size_t)(kv1 + vkb * 4) * Dc + vdb * 4;
      #pragma unroll
      for (int r = 0; r < 4; ++r) vreg[r] = *(const float4*)(vb0 + r * Dc);
    }

    const bool partial = (it == qtile);
    const int  ns = partial ? (wave + 1) : 4;  // live 16-k subtiles

    // ---- S^T = K·Q^T: sacc[s] k = s*16+g*4+r, q = l16 ----
    f32x4 sacc[4];
    #pragma unroll
    for (int s = 0; s < 4; ++s) {
      if (s < ns) {  // wave-uniform
        f32x4 z = {0.f, 0.f, 0.f, 0.f};
        const int row = s * 16 + l16;
        const char* kb = (const char*)Kl + row * 128;
        const int swz = (row & 7) << 4;
        bf16x8 k0 = *(const bf16x8*)(kb + ((g * 16) ^ swz));
        bf16x8 k1 = *(const bf16x8*)(kb + ((64 + g * 16) ^ swz));
        z = __builtin_amdgcn_mfma_f32_16x16x32_bf16(k0, qf[0], z, 0, 0, 0);
        z = __builtin_amdgcn_mfma_f32_16x16x32_bf16(k1, qf[1], z, 0, 0, 0);
        sacc[s] = z;
      } else {
        sacc[s] = f32x4{-INFINITY, -INFINITY, -INFINITY, -INFINITY};
      }
    }
    if (partial) {  // diagonal mask
      #pragma unroll
      for (int s = 0; s < 4; ++s)
        #pragma unroll
        for (int r = 0; r < 4; ++r)
          if (s * 16 + g * 4 + r > wave * 16 + l16) sacc[s][r] = -INFINITY;
    }

    // ---- Online softmax for q-row l16 (4 g-replicas) ----
    float mx = -INFINITY;
    #pragma unroll
    for (int s = 0; s < 4; ++s)
      #pragma unroll
      for (int r = 0; r < 4; ++r) mx = fmaxf(mx, sacc[s][r]);
    mx = fmaxf(mx, __shfl_xor(mx, 16, 64));
    mx = fmaxf(mx, __shfl_xor(mx, 32, 64));
    const float mn = fmaxf(m_run, mx);
    const float f  = __builtin_amdgcn_exp2f(m_run - mn);
    m_run = mn;

    float sum = 0.f;
    bf16x8 pa[2];
    #pragma unroll
    for (int c = 0; c < 2; ++c)
      #pragma unroll
      for (int j = 0; j < 8; ++j) {
        const float pv = __builtin_amdgcn_exp2f(sacc[2 * c + (j >> 2)][j & 3] - mn);
        sum += pv;
        pa[c][j] = (__bf16)pv;
      }
    sum += __shfl_xor(sum, 16, 64);
    sum += __shfl_xor(sum, 32, 64);
    l_run = l_run * f + sum;

    // Rescale O: factor for q = g*4+r lives at lane g*4+r.
    #pragma unroll
    for (int r = 0; r < 4; ++r) {
      const float fo = __shfl(f, g * 4 + r, 64);
      #pragma unroll
      for (int dt = 0; dt < 4; ++dt) o_acc[dt][r] *= fo;
    }

    // ---- PV: O += P(16x64)·V(64x64), both operands in pi k-order ----
    #pragma unroll
    for (int dt = 0; dt < 4; ++dt) {
      const int d = dt * 16 + l16;
      #pragma unroll
      for (int c = 0; c < 2; ++c) {
        const int kc0 = 8 * c + g;
        const int kc1 = 8 * c + 4 + g;
        union { bf16x8 v8; bf16x4 v4[2]; } u;
        u.v4[0] = *(const bf16x4*)((char*)Vt + kc0 * 512 + ((d * 8) ^ (kc0 << 3)));
        u.v4[1] = *(const bf16x4*)((char*)Vt + kc1 * 512 + ((d * 8) ^ (kc1 << 3)));
        o_acc[dt] = __builtin_amdgcn_mfma_f32_16x16x32_bf16(pa[c], u.v8, o_acc[dt], 0, 0, 0);
      }
    }
  }

  // ---- Epilogue: out[b][q][h*64+d] = o / l ----
  #pragma unroll
  for (int r = 0; r < 4; ++r) {
    const float il = __shfl(l_run, g * 4 + r, 64);
    const float inv = 1.f / il;
    float* orow = O + ((size_t)b * Tc + (q0 + g * 4 + r)) * (Hc * Dc) + h * Dc;
    #pragma unroll
    for (int dt = 0; dt < 4; ++dt)
      orow[dt * 16 + l16] = o_acc[dt][r] * inv;
  }
}

extern "C" void kernel_launch(void* const* d_in, const int* in_sizes, int n_in,
                              void* d_out, int out_size, void* d_ws, size_t ws_size,
                              hipStream_t stream) {
  const float* q = (const float*)d_in[0];
  const float* k = (const float*)d_in[1];
  const float* v = (const float*)d_in[2];
  float* out = (float*)d_out;

  dim3 grid(Bc * Hc * (Tc / 64));  // 1024 blocks
  dim3 block(256);                 // 4 waves
  hipLaunchKernelGGL(attn_fwd_kernel, grid, block, 0, stream, q, k, v, out);
}

// Round 5
// 53.091 us; speedup vs baseline: 5.4950x; 1.0033x over previous
//
#include <hip/hip_runtime.h>

// Causal MHA forward: B=2 H=16 T=2048 DH=64, fp32 in/out, bf16 MFMA math.
// Flash-attention, 4 waves/block, wave owns 16 q rows, KBLK=64.
// Swapped QK^T (mfma(K,Q)); P in registers; V^T k-quad LDS layout.
// Each block processes the qtile pair (p, 31-p) sequentially -> all 512
// blocks run exactly 33 k-tile iterations (zero straggler imbalance).
// T13 defer-max, T5 setprio, T14 reg-prefetch of next tile.

constexpr int Bc = 2, Hc = 16, Tc = 2048, Dc = 64;
constexpr float QSCALE = 0.125f * 1.44269504088896340736f; // DH^-0.5 * log2 e

typedef __attribute__((__ext_vector_type__(8))) __bf16 bf16x8;
typedef __attribute__((__ext_vector_type__(4))) __bf16 bf16x4;
typedef __attribute__((__ext_vector_type__(4))) float f32x4;

__global__ __launch_bounds__(256, 4) void attn_fwd_kernel(
    const float* __restrict__ Q,
    const float* __restrict__ K,
    const float* __restrict__ V,
    float* __restrict__ O)
{
  const int tid  = threadIdx.x;
  const int wave = tid >> 6;
  const int lane = tid & 63;
  const int l16  = lane & 15;
  const int g    = lane >> 4;

  // bid = pr*32 + head: consecutive bids (same XCD round-robin class) share
  // a small head set -> K/V stays L2-resident per XCD.
  const int bid  = blockIdx.x;
  const int head = bid & 31;
  const int pr   = bid >> 5;          // 0..15; block does qtiles pr and 31-pr
  const int b = head >> 4, h = head & 15;

  const size_t hoff = (size_t)head * Tc * Dc;
  const float* Qb = Q + hoff;
  const float* Kb = K + hoff;
  const float* Vb = V + hoff;

  // K tile [64 k][64 d] bf16, 128 B rows, byte ^ ((k&7)<<4) swizzle.
  __shared__ __bf16 Kl[64 * 64];
  // V^T k-quads: addr(kc,d) = kc*512 + ((d*8) ^ (kc<<3) ^ (((d>>4)&3)<<3)),
  // +2*(k&3). Conflict-free writes (b64 x16 lanes) and floor reads.
  __shared__ __bf16 Vt[64 * 64];

  // Staging assignments.
  const int krow = tid >> 2;          // K: row; 16-float segment seg
  const int seg  = tid & 3;
  const int kswz = (krow & 7) << 4;
  const int vkb  = tid >> 4;          // V: k-quad block
  const int vdb  = tid & 15;          // V: d-quad
  const int vwx  = (vdb >> 2) << 3;   // ((d>>4)&3)<<3 for d = vdb*4+i

  float4 kreg[4], vreg[4];

  for (int ph = 0; ph < 2; ++ph) {
    const int qtile = ph ? (31 - pr) : pr;
    const int q0 = qtile * 64 + wave * 16;

    // Q as B-operand frag of S^T = K·Q^T: lane l16 = q, regs d = c*32+g*8+j.
    bf16x8 qf[2];
    {
      const float4* qp = (const float4*)(Qb + (size_t)(q0 + l16) * Dc + g * 8);
      #pragma unroll
      for (int c = 0; c < 2; ++c) {
        float4 x0 = qp[c * 8], x1 = qp[c * 8 + 1];
        const float* f0 = (const float*)&x0;
        const float* f1 = (const float*)&x1;
        #pragma unroll
        for (int j = 0; j < 4; ++j) {
          qf[c][j]     = (__bf16)(f0[j] * QSCALE);
          qf[c][4 + j] = (__bf16)(f1[j] * QSCALE);
        }
      }
    }

    f32x4 o_acc[4] = {};
    float m_run = -1e30f, l_run = 0.f;

    const int n_iter = qtile + 1;

    // Prologue: tile 0 into registers.
    {
      const float4* kp4 = (const float4*)(Kb + (size_t)krow * Dc + seg * 16);
      #pragma unroll
      for (int c = 0; c < 4; ++c) kreg[c] = kp4[c];
      const float* vb0 = Vb + (size_t)(vkb * 4) * Dc + vdb * 4;
      #pragma unroll
      for (int r = 0; r < 4; ++r) vreg[r] = *(const float4*)(vb0 + r * Dc);
    }

    for (int it = 0; it < n_iter; ++it) {
      __syncthreads();  // previous tile's LDS reads done (and phase boundary)

      // ---- Write staged registers to LDS ----
      #pragma unroll
      for (int hh = 0; hh < 2; ++hh) {
        const float* x0 = (const float*)&kreg[2 * hh];
        const float* x1 = (const float*)&kreg[2 * hh + 1];
        bf16x8 t;
        #pragma unroll
        for (int j = 0; j < 4; ++j) { t[j] = (__bf16)x0[j]; t[4 + j] = (__bf16)x1[j]; }
        *(bf16x8*)((char*)Kl + krow * 128 + ((seg * 32 + hh * 16) ^ kswz)) = t;
      }
      #pragma unroll
      for (int i = 0; i < 4; ++i) {
        bf16x4 t;
        #pragma unroll
        for (int r = 0; r < 4; ++r) t[r] = (__bf16)((const float*)&vreg[r])[i];
        const int d = vdb * 4 + i;
        *(bf16x4*)((char*)Vt + vkb * 512 + ((d * 8) ^ (vkb << 3) ^ vwx)) = t;
      }
      __syncthreads();  // tile staged

      // ---- T14: issue next tile's global loads before compute ----
      if (it + 1 < n_iter) {
        const int kv1 = (it + 1) * 64;
        const float4* kp4 = (const float4*)(Kb + (size_t)(kv1 + krow) * Dc + seg * 16);
        #pragma unroll
        for (int c = 0; c < 4; ++c) kreg[c] = kp4[c];
        const float* vb0 = Vb + (size_t)(kv1 + vkb * 4) * Dc + vdb * 4;
        #pragma unroll
        for (int r = 0; r < 4; ++r) vreg[r] = *(const float4*)(vb0 + r * Dc);
      }

      const bool partial = (it == qtile);
      const int  ns = partial ? (wave + 1) : 4;  // live 16-k subtiles

      // ---- S^T = K·Q^T: sacc[s] k = s*16+g*4+r, q = l16 ----
      f32x4 sacc[4];
      __builtin_amdgcn_s_setprio(1);
      #pragma unroll
      for (int s = 0; s < 4; ++s) {
        if (s < ns) {  // wave-uniform
          f32x4 z = {0.f, 0.f, 0.f, 0.f};
          const int row = s * 16 + l16;
          const char* kb = (const char*)Kl + row * 128;
          const int swz = (row & 7) << 4;
          bf16x8 k0 = *(const bf16x8*)(kb + ((g * 16) ^ swz));
          bf16x8 k1 = *(const bf16x8*)(kb + ((64 + g * 16) ^ swz));
          z = __builtin_amdgcn_mfma_f32_16x16x32_bf16(k0, qf[0], z, 0, 0, 0);
          z = __builtin_amdgcn_mfma_f32_16x16x32_bf16(k1, qf[1], z, 0, 0, 0);
          sacc[s] = z;
        } else {
          sacc[s] = f32x4{-INFINITY, -INFINITY, -INFINITY, -INFINITY};
        }
      }
      __builtin_amdgcn_s_setprio(0);
      if (partial) {  // diagonal mask
        #pragma unroll
        for (int s = 0; s < 4; ++s)
          #pragma unroll
          for (int r = 0; r < 4; ++r)
            if (s * 16 + g * 4 + r > wave * 16 + l16) sacc[s][r] = -INFINITY;
      }

      // ---- Online softmax for q-row l16 (4 g-replicas) ----
      float mx = -INFINITY;
      #pragma unroll
      for (int s = 0; s < 4; ++s)
        #pragma unroll
        for (int r = 0; r < 4; ++r) mx = fmaxf(mx, sacc[s][r]);
      mx = fmaxf(mx, __shfl_xor(mx, 16, 64));
      mx = fmaxf(mx, __shfl_xor(mx, 32, 64));

      // T13 defer-max: skip rescale while the running max grows < 8 (exp2
      // domain: P bounded by 2^8, f32 l_run has headroom).
      if (!__all(mx <= m_run + 8.0f)) {
        const float mn = fmaxf(m_run, mx);
        const float f  = __builtin_amdgcn_exp2f(m_run - mn);
        m_run = mn;
        l_run *= f;
        #pragma unroll
        for (int r = 0; r < 4; ++r) {
          const float fo = __shfl(f, g * 4 + r, 64);
          #pragma unroll
          for (int dt = 0; dt < 4; ++dt) o_acc[dt][r] *= fo;
        }
      }

      float sum = 0.f;
      bf16x8 pa[2];
      #pragma unroll
      for (int c = 0; c < 2; ++c)
        #pragma unroll
        for (int j = 0; j < 8; ++j) {
          const float pv = __builtin_amdgcn_exp2f(sacc[2 * c + (j >> 2)][j & 3] - m_run);
          sum += pv;
          pa[c][j] = (__bf16)pv;
        }
      sum += __shfl_xor(sum, 16, 64);
      sum += __shfl_xor(sum, 32, 64);
      l_run += sum;

      // ---- PV: O += P(16x64)·V(64x64), both operands in pi k-order ----
      __builtin_amdgcn_s_setprio(1);
      #pragma unroll
      for (int dt = 0; dt < 4; ++dt) {
        const int d = dt * 16 + l16;
        const int dx = (dt & 3) << 3;   // ((d>>4)&3)<<3
        #pragma unroll
        for (int c = 0; c < 2; ++c) {
          const int kc0 = 8 * c + g;
          const int kc1 = 8 * c + 4 + g;
          union { bf16x8 v8; bf16x4 v4[2]; } u;
          u.v4[0] = *(const bf16x4*)((char*)Vt + kc0 * 512 + ((d * 8) ^ (kc0 << 3) ^ dx));
          u.v4[1] = *(const bf16x4*)((char*)Vt + kc1 * 512 + ((d * 8) ^ (kc1 << 3) ^ dx));
          o_acc[dt] = __builtin_amdgcn_mfma_f32_16x16x32_bf16(pa[c], u.v8, o_acc[dt], 0, 0, 0);
        }
      }
      __builtin_amdgcn_s_setprio(0);
    }

    // ---- Epilogue: out[b][q][h*64+d] = o / l ----
    #pragma unroll
    for (int r = 0; r < 4; ++r) {
      const float il = __shfl(l_run, g * 4 + r, 64);
      const float inv = 1.f / il;
      float* orow = O + ((size_t)b * Tc + (q0 + g * 4 + r)) * (Hc * Dc) + h * Dc;
      #pragma unroll
      for (int dt = 0; dt < 4; ++dt)
        orow[dt * 16 + l16] = o_acc[dt][r] * inv;
    }
  }
}

extern "C" void kernel_launch(void* const* d_in, const int* in_sizes, int n_in,
                              void* d_out, int out_size, void* d_ws, size_t ws_size,
                              hipStream_t stream) {
  const float* q = (const float*)d_in[0];
  const float* k = (const float*)d_in[1];
  const float* v = (const float*)d_in[2];
  float* out = (float*)d_out;

  dim3 grid(512);   // 16 qtile-pairs x 32 heads; every block = 33 iterations
  dim3 block(256);  // 4 waves
  hipLaunchKernelGGL(attn_fwd_kernel, grid, block, 0, stream, q, k, v, out);
}

// Round 6
// 49.306 us; speedup vs baseline: 5.9167x; 1.0768x over previous
//
#include <hip/hip_runtime.h>

// Causal MHA forward: B=2 H=16 T=2048 DH=64, fp32 in/out, bf16 MFMA math.
// Flash-attention, 4 waves/block, wave owns 16 q rows, KBLK=64.
// Swapped QK^T (mfma(K,Q)); P in registers; V^T k-quad LDS layout.
// Grid 1024, LPT order (longest qtile first) -> backfill keeps CUs full.
// Double-buffered LDS, ONE barrier per iteration. T13 defer-max, T5
// setprio, T14 reg-prefetch of next tile during compute.

constexpr int Bc = 2, Hc = 16, Tc = 2048, Dc = 64;
constexpr float QSCALE = 0.125f * 1.44269504088896340736f; // DH^-0.5 * log2 e

typedef __attribute__((__ext_vector_type__(8))) __bf16 bf16x8;
typedef __attribute__((__ext_vector_type__(4))) __bf16 bf16x4;
typedef __attribute__((__ext_vector_type__(4))) float f32x4;

__global__ __launch_bounds__(256, 4) void attn_fwd_kernel(
    const float* __restrict__ Q,
    const float* __restrict__ K,
    const float* __restrict__ V,
    float* __restrict__ O)
{
  const int tid  = threadIdx.x;
  const int wave = tid >> 6;
  const int lane = tid & 63;
  const int l16  = lane & 15;
  const int g    = lane >> 4;

  // LPT dispatch: longest blocks (qtile 31) first; short ones backfill.
  const int bid   = blockIdx.x;
  const int head  = bid & 31;
  const int qtile = 31 - (bid >> 5);
  const int b = head >> 4, h = head & 15;
  const int q0 = qtile * 64 + wave * 16;

  const size_t hoff = (size_t)head * Tc * Dc;
  const float* Qb = Q + hoff;
  const float* Kb = K + hoff;
  const float* Vb = V + hoff;

  // Double-buffered tiles (one barrier per iteration).
  // K tile [64 k][64 d] bf16, 128 B rows, byte ^ ((k&7)<<4) swizzle.
  __shared__ __bf16 Kl[2][64 * 64];
  // V^T k-quads: addr(kc,d) = kc*512 + ((d*8) ^ (kc<<3) ^ (((d>>4)&3)<<3))
  // + 2*(k&3). Conflict-free b64 writes and floor reads.
  __shared__ __bf16 Vt[2][64 * 64];

  // Staging assignments.
  const int krow = tid >> 2;          // K: row; 16-float segment seg
  const int seg  = tid & 3;
  const int kswz = (krow & 7) << 4;
  const int vkb  = tid >> 4;          // V: k-quad block
  const int vdb  = tid & 15;          // V: d-quad
  const int vwx  = (vdb >> 2) << 3;   // ((d>>4)&3)<<3 for d = vdb*4+i

  // Q as B-operand frag of S^T = K·Q^T: lane l16 = q, regs d = c*32+g*8+j.
  bf16x8 qf[2];
  {
    const float4* qp = (const float4*)(Qb + (size_t)(q0 + l16) * Dc + g * 8);
    #pragma unroll
    for (int c = 0; c < 2; ++c) {
      float4 x0 = qp[c * 8], x1 = qp[c * 8 + 1];
      const float* f0 = (const float*)&x0;
      const float* f1 = (const float*)&x1;
      #pragma unroll
      for (int j = 0; j < 4; ++j) {
        qf[c][j]     = (__bf16)(f0[j] * QSCALE);
        qf[c][4 + j] = (__bf16)(f1[j] * QSCALE);
      }
    }
  }

  f32x4 o_acc[4] = {};
  float m_run = -1e30f, l_run = 0.f;

  const int n_iter = qtile + 1;
  float4 kreg[4], vreg[4];

  // ---- Prologue: tile 0 -> regs -> buf 0 (visibility via iter-0 barrier) --
  {
    const float4* kp4 = (const float4*)(Kb + (size_t)krow * Dc + seg * 16);
    #pragma unroll
    for (int c = 0; c < 4; ++c) kreg[c] = kp4[c];
    const float* vb0 = Vb + (size_t)(vkb * 4) * Dc + vdb * 4;
    #pragma unroll
    for (int r = 0; r < 4; ++r) vreg[r] = *(const float4*)(vb0 + r * Dc);

    #pragma unroll
    for (int hh = 0; hh < 2; ++hh) {
      const float* x0 = (const float*)&kreg[2 * hh];
      const float* x1 = (const float*)&kreg[2 * hh + 1];
      bf16x8 t;
      #pragma unroll
      for (int j = 0; j < 4; ++j) { t[j] = (__bf16)x0[j]; t[4 + j] = (__bf16)x1[j]; }
      *(bf16x8*)((char*)Kl[0] + krow * 128 + ((seg * 32 + hh * 16) ^ kswz)) = t;
    }
    #pragma unroll
    for (int i = 0; i < 4; ++i) {
      bf16x4 t;
      #pragma unroll
      for (int r = 0; r < 4; ++r) t[r] = (__bf16)((const float*)&vreg[r])[i];
      const int d = vdb * 4 + i;
      *(bf16x4*)((char*)Vt[0] + vkb * 512 + ((d * 8) ^ (vkb << 3) ^ vwx)) = t;
    }
  }

  for (int it = 0; it < n_iter; ++it) {
    __syncthreads();  // buf[it&1] fully staged; other buffer free to write
    const int cur = it & 1;

    // ---- T14: issue next tile's global loads (land during compute) ----
    const bool more = (it + 1 < n_iter);
    if (more) {
      const int kv1 = (it + 1) * 64;
      const float4* kp4 = (const float4*)(Kb + (size_t)(kv1 + krow) * Dc + seg * 16);
      #pragma unroll
      for (int c = 0; c < 4; ++c) kreg[c] = kp4[c];
      const float* vb0 = Vb + (size_t)(kv1 + vkb * 4) * Dc + vdb * 4;
      #pragma unroll
      for (int r = 0; r < 4; ++r) vreg[r] = *(const float4*)(vb0 + r * Dc);
    }

    const bool partial = (it == qtile);
    const int  ns = partial ? (wave + 1) : 4;  // live 16-k subtiles

    // ---- S^T = K·Q^T: sacc[s] k = s*16+g*4+r, q = l16 ----
    f32x4 sacc[4];
    __builtin_amdgcn_s_setprio(1);
    #pragma unroll
    for (int s = 0; s < 4; ++s) {
      if (s < ns) {  // wave-uniform
        f32x4 z = {0.f, 0.f, 0.f, 0.f};
        const int row = s * 16 + l16;
        const char* kb = (const char*)Kl[cur] + row * 128;
        const int swz = (row & 7) << 4;
        bf16x8 k0 = *(const bf16x8*)(kb + ((g * 16) ^ swz));
        bf16x8 k1 = *(const bf16x8*)(kb + ((64 + g * 16) ^ swz));
        z = __builtin_amdgcn_mfma_f32_16x16x32_bf16(k0, qf[0], z, 0, 0, 0);
        z = __builtin_amdgcn_mfma_f32_16x16x32_bf16(k1, qf[1], z, 0, 0, 0);
        sacc[s] = z;
      } else {
        sacc[s] = f32x4{-INFINITY, -INFINITY, -INFINITY, -INFINITY};
      }
    }
    __builtin_amdgcn_s_setprio(0);
    if (partial) {  // diagonal mask
      #pragma unroll
      for (int s = 0; s < 4; ++s)
        #pragma unroll
        for (int r = 0; r < 4; ++r)
          if (s * 16 + g * 4 + r > wave * 16 + l16) sacc[s][r] = -INFINITY;
    }

    // ---- Online softmax for q-row l16 (4 g-replicas) ----
    float mx = -INFINITY;
    #pragma unroll
    for (int s = 0; s < 4; ++s)
      #pragma unroll
      for (int r = 0; r < 4; ++r) mx = fmaxf(mx, sacc[s][r]);
    mx = fmaxf(mx, __shfl_xor(mx, 16, 64));
    mx = fmaxf(mx, __shfl_xor(mx, 32, 64));

    // T13 defer-max: skip rescale while max growth < 8 (P bounded by 2^8).
    if (!__all(mx <= m_run + 8.0f)) {
      const float mn = fmaxf(m_run, mx);
      const float f  = __builtin_amdgcn_exp2f(m_run - mn);
      m_run = mn;
      l_run *= f;
      #pragma unroll
      for (int r = 0; r < 4; ++r) {
        const float fo = __shfl(f, g * 4 + r, 64);
        #pragma unroll
        for (int dt = 0; dt < 4; ++dt) o_acc[dt][r] *= fo;
      }
    }

    float sum = 0.f;
    bf16x8 pa[2];
    #pragma unroll
    for (int c = 0; c < 2; ++c)
      #pragma unroll
      for (int j = 0; j < 8; ++j) {
        const float pv = __builtin_amdgcn_exp2f(sacc[2 * c + (j >> 2)][j & 3] - m_run);
        sum += pv;
        pa[c][j] = (__bf16)pv;
      }
    sum += __shfl_xor(sum, 16, 64);
    sum += __shfl_xor(sum, 32, 64);
    l_run += sum;

    // ---- PV: O += P(16x64)·V(64x64), both operands in pi k-order ----
    __builtin_amdgcn_s_setprio(1);
    #pragma unroll
    for (int dt = 0; dt < 4; ++dt) {
      const int d = dt * 16 + l16;
      const int dx = (dt & 3) << 3;   // ((d>>4)&3)<<3
      #pragma unroll
      for (int c = 0; c < 2; ++c) {
        const int kc0 = 8 * c + g;
        const int kc1 = 8 * c + 4 + g;
        union { bf16x8 v8; bf16x4 v4[2]; } u;
        u.v4[0] = *(const bf16x4*)((char*)Vt[cur] + kc0 * 512 + ((d * 8) ^ (kc0 << 3) ^ dx));
        u.v4[1] = *(const bf16x4*)((char*)Vt[cur] + kc1 * 512 + ((d * 8) ^ (kc1 << 3) ^ dx));
        o_acc[dt] = __builtin_amdgcn_mfma_f32_16x16x32_bf16(pa[c], u.v8, o_acc[dt], 0, 0, 0);
      }
    }
    __builtin_amdgcn_s_setprio(0);

    // ---- Write prefetched tile into the other buffer (no barrier needed:
    // all waves finished reading it at iteration it-1, enforced by the
    // barrier at the top of THIS iteration) ----
    if (more) {
      const int nxt = cur ^ 1;
      #pragma unroll
      for (int hh = 0; hh < 2; ++hh) {
        const float* x0 = (const float*)&kreg[2 * hh];
        const float* x1 = (const float*)&kreg[2 * hh + 1];
        bf16x8 t;
        #pragma unroll
        for (int j = 0; j < 4; ++j) { t[j] = (__bf16)x0[j]; t[4 + j] = (__bf16)x1[j]; }
        *(bf16x8*)((char*)Kl[nxt] + krow * 128 + ((seg * 32 + hh * 16) ^ kswz)) = t;
      }
      #pragma unroll
      for (int i = 0; i < 4; ++i) {
        bf16x4 t;
        #pragma unroll
        for (int r = 0; r < 4; ++r) t[r] = (__bf16)((const float*)&vreg[r])[i];
        const int d = vdb * 4 + i;
        *(bf16x4*)((char*)Vt[nxt] + vkb * 512 + ((d * 8) ^ (vkb << 3) ^ vwx)) = t;
      }
    }
  }

  // ---- Epilogue: out[b][q][h*64+d] = o / l ----
  #pragma unroll
  for (int r = 0; r < 4; ++r) {
    const float il = __shfl(l_run, g * 4 + r, 64);
    const float inv = 1.f / il;
    float* orow = O + ((size_t)b * Tc + (q0 + g * 4 + r)) * (Hc * Dc) + h * Dc;
    #pragma unroll
    for (int dt = 0; dt < 4; ++dt)
      orow[dt * 16 + l16] = o_acc[dt][r] * inv;
  }
}

extern "C" void kernel_launch(void* const* d_in, const int* in_sizes, int n_in,
                              void* d_out, int out_size, void* d_ws, size_t ws_size,
                              hipStream_t stream) {
  const float* q = (const float*)d_in[0];
  const float* k = (const float*)d_in[1];
  const float* v = (const float*)d_in[2];
  float* out = (float*)d_out;

  dim3 grid(1024);  // 32 qtiles (longest first) x 32 heads
  dim3 block(256);  // 4 waves
  hipLaunchKernelGGL(attn_fwd_kernel, grid, block, 0, stream, q, k, v, out);
}